// Round 7
// baseline (990.876 us; speedup 1.0000x reference)
//
#include <hip/hip_runtime.h>
#include <hip/hip_bf16.h>

// Problem constants
constexpr int B_   = 8;
constexpr int D_   = 1024;
constexpr int T_   = 512;
constexpr int HID_ = 256;
constexpr int NH_  = 4;
constexpr int NL_  = 2;
constexpr float ALPHA_ = 0.2f;
constexpr float EPS_   = 1e-5f;
constexpr int OUT_ = 64;
constexpr int M_ = B_ * D_;      // 8192 rows
constexpr int DT_ = D_ * T_;     // 524288
constexpr int KIN_ = 2 * T_;     // 1024
constexpr int CKS_ = 132;        // checkpoint row stride (floats)
constexpr int NCH_ = 64;         // prefix chunks per bh
constexpr int CR_  = 16;         // ranks per chunk
constexpr int NB_  = 512;        // mega-kernel grid (co-resident: <=2 blocks/CU needed,
                                 // LDS 36.9KB -> 4/CU, VGPR<=256 via launch_bounds -> >=2/CU)

typedef __attribute__((ext_vector_type(8))) short short8;   // 8 bf16 (4 VGPRs)
typedef __attribute__((ext_vector_type(4))) float floatx4;  // 4 fp32 acc

__device__ __forceinline__ unsigned short f2bf(float f) {
    unsigned int u = __float_as_uint(f);
    unsigned int r = u + 0x7fffu + ((u >> 16) & 1u);   // round-to-nearest-even
    return (unsigned short)(r >> 16);
}
__device__ __forceinline__ float bf2f(unsigned short u) {
    return __uint_as_float(((unsigned int)u) << 16);
}
// monotone float<->uint key for atomicMax on signed floats
__device__ __forceinline__ unsigned int kenc(float f) {
    unsigned int u = __float_as_uint(f);
    return (u & 0x80000000u) ? ~u : (u | 0x80000000u);
}
__device__ __forceinline__ float kdec(unsigned int k) {
    unsigned int u = (k & 0x80000000u) ? (k ^ 0x80000000u) : ~k;
    return __uint_as_float(u);
}

// Software grid barrier: distinct counter per use (no reset/sense hazard).
// Release: __threadfence + atomicAdd (device scope). Acquire: agent-scope load.
__device__ __forceinline__ void gridbar(unsigned int* bar) {
    __syncthreads();
    if (threadIdx.x == 0) {
        __threadfence();
        atomicAdd(bar, 1u);
        while (__hip_atomic_load(bar, __ATOMIC_ACQUIRE, __HIP_MEMORY_SCOPE_AGENT)
               < (unsigned)NB_)
            __builtin_amdgcn_s_sleep(2);
    }
    __syncthreads();
}

__global__ __launch_bounds__(256) void init_k(unsigned int* __restrict__ bar) {
    if (threadIdx.x < 64) bar[threadIdx.x] = 0u;
}

struct GemmSm {
    unsigned short As[2][64 * 72];   // 18 KB, padded
    unsigned short Bs[2][64 * 72];   // 18 KB
};

// r5-proven BM=64 BN=64 BK=64 MFMA tile, as a device function.
// MODE 0: fp32 C (+bias). MODE 1: + bf16 copy. MODE 2: hwN + s_l/s_r/rmax.
template <int MODE>
__device__ void gemm_tile(
        const unsigned short* __restrict__ A,    // M x K bf16
        const unsigned short* __restrict__ Bt,   // N x K bf16 (B transposed)
        const float* __restrict__ bias,
        float* __restrict__ C,
        unsigned short* __restrict__ Cb,
        const float* __restrict__ ga,
        float* __restrict__ s_l,
        float* __restrict__ s_r,
        unsigned int* __restrict__ rmaxkey,
        int Nsz, int Ksz, int bx, int by, GemmSm& sm) {
    __syncthreads();                              // LDS reuse guard
    int tid = threadIdx.x;
    int wave = tid >> 6, lane = tid & 63;
    int q = lane >> 4, r16 = lane & 15;
    int rowbase = by * 64;
    int colbase = bx * 64;

    int srow = tid >> 3, sk = (tid & 7) * 8;
    const unsigned short* Ap0 = A + (size_t)(rowbase + srow) * Ksz + sk;
    const unsigned short* Ap1 = A + (size_t)(rowbase + srow + 32) * Ksz + sk;
    const unsigned short* Bp0 = Bt + (size_t)(colbase + srow) * Ksz + sk;
    const unsigned short* Bp1 = Bt + (size_t)(colbase + srow + 32) * Ksz + sk;
    int la0 = srow * 72 + sk, la1 = (srow + 32) * 72 + sk;

    floatx4 acc[4];
#pragma unroll
    for (int i = 0; i < 4; i++) acc[i] = (floatx4)0.f;

    uint4 pa0 = *(const uint4*)Ap0, pa1 = *(const uint4*)Ap1;
    uint4 pb0 = *(const uint4*)Bp0, pb1 = *(const uint4*)Bp1;
    *(uint4*)&sm.As[0][la0] = pa0;
    *(uint4*)&sm.As[0][la1] = pa1;
    *(uint4*)&sm.Bs[0][la0] = pb0;
    *(uint4*)&sm.Bs[0][la1] = pb1;

    int nk = Ksz >> 6;
    for (int it = 0; it < nk; it++) {
        int cur = it & 1;
        __syncthreads();
        if (it + 1 < nk) {
            int kt = (it + 1) << 6;
            pa0 = *(const uint4*)(Ap0 + kt);
            pa1 = *(const uint4*)(Ap1 + kt);
            pb0 = *(const uint4*)(Bp0 + kt);
            pb1 = *(const uint4*)(Bp1 + kt);
        }
#pragma unroll
        for (int t = 0; t < 2; t++) {
            short8 a = *(const short8*)&sm.As[cur][(wave * 16 + r16) * 72 + t * 32 + q * 8];
#pragma unroll
            for (int ni = 0; ni < 4; ni++) {
                short8 b = *(const short8*)&sm.Bs[cur][(ni * 16 + r16) * 72 + t * 32 + q * 8];
                acc[ni] = __builtin_amdgcn_mfma_f32_16x16x32_bf16(a, b, acc[ni], 0, 0, 0);
            }
        }
        if (it + 1 < nk) {
            int nxt = cur ^ 1;
            *(uint4*)&sm.As[nxt][la0] = pa0;
            *(uint4*)&sm.As[nxt][la1] = pa1;
            *(uint4*)&sm.Bs[nxt][la0] = pb0;
            *(uint4*)&sm.Bs[nxt][la1] = pb1;
        }
    }
    // epilogue. C/D map: col=lane&15, row=(lane>>4)*4+reg
    if constexpr (MODE == 2) {
        int bhh = ((rowbase >> 10) << 2) + bx;    // b*4 + h
        int nb0 = rowbase & (D_ - 1);
        int nb = nb0 + wave * 16;
        const float* gab = ga + bx * 2 * OUT_;
        float al4[4], ar4[4];
#pragma unroll
        for (int ni = 0; ni < 4; ni++) {
            al4[ni] = gab[ni * 16 + r16];
            ar4[ni] = gab[OUT_ + ni * 16 + r16];
        }
        float slv[4], srv[4];
#pragma unroll
        for (int rr = 0; rr < 4; rr++) {
            float s1 = 0.f, s2 = 0.f;
#pragma unroll
            for (int ni = 0; ni < 4; ni++) {
                s1 += acc[ni][rr] * al4[ni];
                s2 += acc[ni][rr] * ar4[ni];
            }
            slv[rr] = s1;
            srv[rr] = s2;
        }
#pragma unroll
        for (int off = 1; off < 16; off <<= 1) {
#pragma unroll
            for (int rr = 0; rr < 4; rr++) {
                slv[rr] += __shfl_xor(slv[rr], off, 64);
                srv[rr] += __shfl_xor(srv[rr], off, 64);
            }
        }
        {
            int rsel = r16 & 3;
            float sv = (rsel == 0) ? slv[0] : (rsel == 1) ? slv[1] : (rsel == 2) ? slv[2] : slv[3];
            float rv = (rsel == 0) ? srv[0] : (rsel == 1) ? srv[1] : (rsel == 2) ? srv[2] : srv[3];
            int n = nb + q * 4 + rsel;
            if (r16 < 4)                 s_l[bhh * D_ + n] = sv;
            else if (r16 >= 8 && r16 < 12) s_r[bhh * D_ + n] = rv;
        }
        float mx = fmaxf(fmaxf(srv[0], srv[1]), fmaxf(srv[2], srv[3]));
        mx = fmaxf(mx, __shfl_xor(mx, 16, 64));
        mx = fmaxf(mx, __shfl_xor(mx, 32, 64));
        if (lane == 0) atomicMax(&rmaxkey[bhh], kenc(mx));
        // hwN tile via LDS staging -> coalesced uint4 rows
        __syncthreads();
        unsigned short* st = &sm.As[0][0];
#pragma unroll
        for (int ni = 0; ni < 4; ni++)
#pragma unroll
            for (int rr = 0; rr < 4; rr++)
                st[(wave * 16 + q * 4 + rr) * 72 + ni * 16 + r16] = f2bf(acc[ni][rr]);
        __syncthreads();
#pragma unroll
        for (int i = 0; i < 2; i++) {
            int idx = tid * 2 + i;                 // 64 rows x 8 segs
            int row = idx >> 3, seg = idx & 7;
            uint4 v = *(const uint4*)&st[row * 72 + seg * 8];
            *(uint4*)&Cb[((size_t)bhh << 16) + ((size_t)(nb0 + row) << 6) + seg * 8] = v;
        }
    } else {
#pragma unroll
        for (int rr = 0; rr < 4; rr++) {
            int row = rowbase + wave * 16 + q * 4 + rr;
#pragma unroll
            for (int ni = 0; ni < 4; ni++) {
                int col = colbase + ni * 16 + r16;
                float v = acc[ni][rr] + (bias ? bias[col] : 0.f);
                C[(size_t)row * Nsz + col] = v;
                if constexpr (MODE == 1) Cb[(size_t)row * Nsz + col] = f2bf(v);
            }
        }
    }
}

// ---------------------------------------------------------------------------
// Mega-kernel: whole pipeline, 512 blocks x 256 threads, 12 grid barriers.
// ---------------------------------------------------------------------------
__global__ __launch_bounds__(256, 2) void mega_k(
        const float* __restrict__ X, const float* __restrict__ Mk,
        const float* __restrict__ W_in, const float* __restrict__ b_in,
        const float* __restrict__ gatW, const float* __restrict__ gat_a,
        const float* __restrict__ ln_g, const float* __restrict__ ln_b,
        const float* __restrict__ W_out, const float* __restrict__ b_out,
        float* __restrict__ out,
        unsigned short* __restrict__ Ain, unsigned short* __restrict__ hwN,
        float* __restrict__ ck, float* __restrict__ csum, float* __restrict__ csca,
        float* __restrict__ wm, float* __restrict__ srtb, int* __restrict__ sig,
        float* __restrict__ hbuf, unsigned short* __restrict__ hbf,
        unsigned short* __restrict__ Wt_in, unsigned short* __restrict__ Wcat,
        unsigned short* __restrict__ WtO,
        float* __restrict__ slb, float* __restrict__ srb,
        unsigned int* __restrict__ rmaxkey, unsigned int* __restrict__ bar) {
    __shared__ union {
        GemmSm g;                                          // 36.9 KB
        struct { float skey[1024]; short part[4][64]; } rk;
        struct { float srtL[4][1024]; float hnew[16][260];
                 float ckT1[4][64]; float qTs[4][2];
                 float pdF[64][2]; int pdT[64]; } rl;      // 34.9 KB
    } sm;
    const int blk = blockIdx.x, tid = threadIdx.x;
    const int gtid = blk * 256 + tid;

    // ---- Ph0: prep (imputation + weight transposes + rmax init) ----
    {
        int idx4 = gtid * 4;                       // over D*T, exactly covered
        int t = idx4 & (T_ - 1);
        int d = idx4 >> 9;
        float4 x[B_], m[B_];
        float4 s = {0, 0, 0, 0}, c = {0, 0, 0, 0};
#pragma unroll
        for (int b = 0; b < B_; b++) {
            x[b] = *(const float4*)&X[(size_t)b * DT_ + idx4];
            m[b] = *(const float4*)&Mk[(size_t)b * DT_ + idx4];
            s.x += x[b].x * m[b].x; s.y += x[b].y * m[b].y;
            s.z += x[b].z * m[b].z; s.w += x[b].w * m[b].w;
            c.x += m[b].x; c.y += m[b].y; c.z += m[b].z; c.w += m[b].w;
        }
        float4 pm;
        pm.x = s.x / (c.x + 1e-10f); pm.y = s.y / (c.y + 1e-10f);
        pm.z = s.z / (c.z + 1e-10f); pm.w = s.w / (c.w + 1e-10f);
#pragma unroll
        for (int b = 0; b < B_; b++) {
            size_t row = (size_t)b * D_ + d;
            ushort4 xm, mk;
            xm.x = f2bf(x[b].x * m[b].x + (1.f - m[b].x) * pm.x);
            xm.y = f2bf(x[b].y * m[b].y + (1.f - m[b].y) * pm.y);
            xm.z = f2bf(x[b].z * m[b].z + (1.f - m[b].z) * pm.z);
            xm.w = f2bf(x[b].w * m[b].w + (1.f - m[b].w) * pm.w);
            mk.x = f2bf(m[b].x); mk.y = f2bf(m[b].y);
            mk.z = f2bf(m[b].z); mk.w = f2bf(m[b].w);
            *(ushort4*)&Ain[row * KIN_ + t]      = xm;
            *(ushort4*)&Ain[row * KIN_ + T_ + t] = mk;
        }
#pragma unroll
        for (int k4 = 0; k4 < 4; ++k4) {
            int idx = gtid + k4 * 131072;
            if (idx < 64) rmaxkey[idx] = 0u;
            if (idx < 262144) {
                int n = idx >> 10, k = idx & 1023;
                Wt_in[idx] = f2bf(W_in[(size_t)k * HID_ + n]);
            } else if (idx < 393216) {
                int j = idx - 262144;
                int l = j >> 16, n = (j >> 8) & 255, k = j & 255;
                int h = n >> 6, e = n & 63;
                Wcat[j] = f2bf(gatW[(((size_t)(l * NH_ + h) * HID_) + k) * OUT_ + e]);
            } else {
                int j = idx - 393216;
                int n = j >> 8, k = j & 255;
                WtO[j] = f2bf(W_out[(size_t)k * T_ + n]);
            }
        }
    }
    int bi = 0;
    gridbar(&bar[bi++]);
    // ---- Ph1: gemm1 (512 tiles = 4 x 128) ----
    gemm_tile<1>(Ain, Wt_in, b_in, hbuf, hbf, nullptr, nullptr, nullptr, nullptr,
                 HID_, KIN_, blk & 3, blk >> 2, sm.g);

    for (int l = 0; l < NL_; ++l) {
        unsigned int* rmxl = rmaxkey + l * 32;
        gridbar(&bar[bi++]);
        // ---- gemm2: hW + s_l/s_r/rmax ----
        gemm_tile<2>(hbf, Wcat + (size_t)l * HID_ * HID_, nullptr, nullptr, hwN,
                     gat_a + (size_t)l * NH_ * 2 * OUT_, slb, srb, rmxl,
                     HID_, HID_, blk & 3, blk >> 2, sm.g);
        gridbar(&bar[bi++]);
        // ---- rank: counting sort, block = (bh, seg of 64) ----
        {
            int bh = blk >> 4, seg = blk & 15;
            *(float4*)&sm.rk.skey[tid * 4] = *(const float4*)&srb[bh * D_ + tid * 4];
            __syncthreads();
            int lane = tid & 63, w4 = tid >> 6;
            int el = seg * 64 + lane;
            float key = sm.rk.skey[el];
            int cnt = 0;
#pragma unroll 4
            for (int m = w4 * 256; m < w4 * 256 + 256; ++m) {
                float km = sm.rk.skey[m];
                cnt += (km < key) || (km == key && m < el);
            }
            sm.rk.part[w4][lane] = (short)cnt;
            __syncthreads();
            if (tid < 64) {
                int rank = sm.rk.part[0][tid] + sm.rk.part[1][tid] +
                           sm.rk.part[2][tid] + sm.rk.part[3][tid];
                int elg = seg * 64 + tid;
                float kk = sm.rk.skey[elg];
                float rm = kdec(rmxl[bh]);
                float u = kk - rm;                 // <= 0
                srtb[bh * D_ + rank] = kk;
                sig[bh * D_ + rank] = elg;
                *(float2*)&wm[(size_t)(bh * D_ + rank) * 2] =
                    float2{__expf(u), __expf(ALPHA_ * u)};
            }
        }
        gridbar(&bar[bi++]);
        // ---- chunksum: wave = (bh, c), CR=16, all 2048 waves active ----
        {
            int gwv = gtid >> 6;
            int bh = gwv >> 6, c = gwv & 63;
            int e = tid & 63;
            const unsigned short* vb = hwN + ((size_t)bh << 16);
            int t0 = c * CR_;
            float a1 = 0.f, a2 = 0.f, q1 = 0.f, q2 = 0.f;
#pragma unroll 4
            for (int t = t0; t < t0 + CR_; ++t) {
                float2 ww = *(const float2*)&wm[(size_t)(bh * D_ + t) * 2];
                float v = bf2f(vb[((size_t)sig[bh * D_ + t] << 6) + e]);
                a1 = fmaf(ww.x, v, a1);
                a2 = fmaf(ww.y, v, a2);
                q1 += ww.x; q2 += ww.y;
            }
            *(float2*)&csum[(((size_t)bh * NCH_ + c) * 64 + e) * 2] = float2{a1, a2};
            if (e == 0) *(float2*)&csca[((size_t)bh * NCH_ + c) * 2] = float2{q1, q2};
        }
        gridbar(&bar[bi++]);
        // ---- ckwrite: offsets + stream per-rank exclusive checkpoints ----
        {
            int gwv = gtid >> 6;
            int bh = gwv >> 6, c = gwv & 63;
            int e = tid & 63;
            float r1 = 0.f, r2 = 0.f, p1 = 0.f, p2 = 0.f;
            for (int cc = 0; cc < c; ++cc) {
                float2 s2 = *(const float2*)&csum[(((size_t)bh * NCH_ + cc) * 64 + e) * 2];
                float2 sc = *(const float2*)&csca[((size_t)bh * NCH_ + cc) * 2];
                r1 += s2.x; r2 += s2.y;
                p1 += sc.x; p2 += sc.y;
            }
            const unsigned short* vb = hwN + ((size_t)bh << 16);
            float* ckb = ck + (size_t)bh * 1025 * CKS_;
            int t0 = c * CR_;
            for (int t = t0; t < t0 + CR_; ++t) {
                *(float2*)&ckb[(size_t)t * CKS_ + 2 * e] = float2{r1, r2};
                if (e == 0) *(float2*)&ckb[(size_t)t * CKS_ + 128] = float2{p1, p2};
                float2 ww = *(const float2*)&wm[(size_t)(bh * D_ + t) * 2];
                float v = bf2f(vb[((size_t)sig[bh * D_ + t] << 6) + e]);
                r1 = fmaf(ww.x, v, r1);
                r2 = fmaf(ww.y, v, r2);
                p1 += ww.x; p2 += ww.y;
            }
            if (c == NCH_ - 1) {   // totals row 1024, same fp chain => exact endpoint
                *(float2*)&ckb[(size_t)1024 * CKS_ + 2 * e] = float2{r1, r2};
                if (e == 0) *(float2*)&ckb[(size_t)1024 * CKS_ + 128] = float2{p1, p2};
            }
        }
        gridbar(&bar[bi++]);
        // ---- rowln: 16 rows/block, bsearch + ck row + residual + LN ----
        {
            int b = blk >> 6;
            int d0 = (blk & 63) << 4;
            for (int i = tid; i < 1024; i += 256) {
#pragma unroll
                for (int hh = 0; hh < 4; ++hh)
                    sm.rl.srtL[hh][i] = srtb[(size_t)(b * 4 + hh) * D_ + i];
            }
            {
                int hh = tid >> 6, e = tid & 63;
                sm.rl.ckT1[hh][e] =
                    ck[((size_t)((b * 4 + hh) * 1025 + 1024)) * CKS_ + 2 * e];
            }
            if (tid < 8) {
                int hh = tid >> 1;
                sm.rl.qTs[hh][tid & 1] =
                    ck[((size_t)((b * 4 + hh) * 1025 + 1024)) * CKS_ + 128 + (tid & 1)];
            }
            __syncthreads();
            if (tid < 64) {
                int r = tid & 15, h4 = tid >> 4;
                int bh = b * 4 + h4;
                float sl = slb[bh * D_ + d0 + r];
                float rm = kdec(rmxl[bh]);
                float x = sl + rm;
                float Mn = fmaxf(x, ALPHA_ * x);
                float A  = __expf(x - Mn);
                float B2 = __expf(ALPHA_ * x - Mn);
                float key = -sl;
                int lo = 0, hi = 1024;
                while (lo < hi) {
                    int mid = (lo + hi) >> 1;
                    if (sm.rl.srtL[h4][mid] < key) lo = mid + 1; else hi = mid;
                }
                float2 qs = *(const float2*)&ck[((size_t)(bh * 1025 + lo)) * CKS_ + 128];
                float den = A * (sm.rl.qTs[h4][0] - qs.x) + B2 * qs.y;
                float inv = 1.f / den;
                sm.rl.pdF[tid][0] = A * inv;
                sm.rl.pdF[tid][1] = B2 * inv;
                sm.rl.pdT[tid] = lo;
            }
            __syncthreads();
            int w4 = tid >> 6, e = tid & 63;
            for (int p = w4; p < 64; p += 4) {
                int r = p & 15, h4 = p >> 4;
                int bh = b * 4 + h4;
                float2 P = *(const float2*)
                    &ck[((size_t)(bh * 1025 + sm.rl.pdT[p])) * CKS_ + 2 * e];
                sm.rl.hnew[r][h4 * 64 + e] =
                    sm.rl.pdF[p][0] * (sm.rl.ckT1[h4][e] - P.x) + sm.rl.pdF[p][1] * P.y;
            }
            __syncthreads();
            const float* g  = ln_g + (size_t)l * HID_;
            const float* bb = ln_b + (size_t)l * HID_;
#pragma unroll
            for (int j = 0; j < 4; ++j) {
                int rr = w4 * 4 + j;
                size_t grow = (((size_t)b << 10) + d0 + rr) << 8;   // *HID_
                float4 a  = *(const float4*)&hbuf[grow + e * 4];
                float4 nv = *(const float4*)&sm.rl.hnew[rr][e * 4];
                float4 v = {a.x + nv.x, a.y + nv.y, a.z + nv.z, a.w + nv.w};
                float s = v.x + v.y + v.z + v.w;
#pragma unroll
                for (int off = 1; off < 64; off <<= 1) s += __shfl_xor(s, off, 64);
                float mu = s * (1.f / HID_);
                float4 dd = {v.x - mu, v.y - mu, v.z - mu, v.w - mu};
                float s2 = dd.x * dd.x + dd.y * dd.y + dd.z * dd.z + dd.w * dd.w;
#pragma unroll
                for (int off = 1; off < 64; off <<= 1) s2 += __shfl_xor(s2, off, 64);
                float rs = rsqrtf(s2 * (1.f / HID_) + EPS_);
                float4 gg  = *(const float4*)&g[e * 4];
                float4 bv  = *(const float4*)&bb[e * 4];
                float4 res;
                res.x = dd.x * rs * gg.x + bv.x;
                res.y = dd.y * rs * gg.y + bv.y;
                res.z = dd.z * rs * gg.z + bv.z;
                res.w = dd.w * rs * gg.w + bv.w;
                *(float4*)&hbuf[grow + e * 4] = res;
                ushort4 pk = {f2bf(res.x), f2bf(res.y), f2bf(res.z), f2bf(res.w)};
                *(ushort4*)&hbf[grow + e * 4] = pk;
            }
        }
    }
    gridbar(&bar[bi++]);
    // ---- gemmout: 1024 tiles (8 x 128), 2 per block ----
#pragma unroll
    for (int k = 0; k < 2; ++k) {
        int tt = blk * 2 + k;
        gemm_tile<0>(hbf, WtO, b_out, out, nullptr, nullptr, nullptr, nullptr,
                     nullptr, T_, HID_, tt & 7, tt >> 3, sm.g);
    }
}

// ---------------------------------------------------------------------------
extern "C" void kernel_launch(void* const* d_in, const int* in_sizes, int n_in,
                              void* d_out, int out_size, void* d_ws, size_t ws_size,
                              hipStream_t stream) {
    const float* X_obs = (const float*)d_in[0];
    const float* mask  = (const float*)d_in[1];
    const float* W_in  = (const float*)d_in[2];
    const float* b_in  = (const float*)d_in[3];
    const float* gat_W = (const float*)d_in[4];
    const float* gat_a = (const float*)d_in[5];
    const float* ln_g  = (const float*)d_in[6];
    const float* ln_b  = (const float*)d_in[7];
    const float* W_out = (const float*)d_in[8];
    const float* b_out = (const float*)d_in[9];
    float* out = (float*)d_out;

    // Workspace layout:
    //  [0,16M):    Ain bf16 (M x 1024), dead after gemm1; hwN bf16 overlays [0,4M)
    //  [4M,20.6M): ck fp32 [32][1025][132]
    //  [20.75M):   csca (16K)   [21M,22M): csum (1M)
    //  [22M):      wm (256K)  [22.5M): srt (128K)  [22.75M): sig (128K)
    //  [23M,31M):  hbuf fp32 (M x 256)
    //  [31M,35M):  hbf bf16 (M x 256)
    //  [35M,+):    Wt_in, Wcat, WtO (bf16), slb/srb (fp32), rmaxkey (uint[64])
    //  [40M):      bar (uint[64])
    char* base = (char*)d_ws;
    unsigned short* Ain = (unsigned short*)base;
    unsigned short* hwN = (unsigned short*)base;
    float* ck   = (float*)(base + (4u << 20));
    float* csca = (float*)(base + (20u << 20) + (768u << 10));
    float* csum = (float*)(base + (21u << 20));
    float* wm   = (float*)(base + (22u << 20));
    float* srtb = (float*)(base + (22u << 20) + (512u << 10));
    int*   sig  = (int*)(base + (22u << 20) + (768u << 10));
    float* hbuf = (float*)(base + (23u << 20));
    unsigned short* hbf   = (unsigned short*)(base + (31u << 20));
    unsigned short* Wt_in = (unsigned short*)(base + (35u << 20));
    unsigned short* Wcat  = Wt_in + (size_t)HID_ * KIN_;        // 256*1024
    unsigned short* WtO   = Wcat + (size_t)NL_ * HID_ * HID_;   // 2*256*256
    float* slb = (float*)(WtO + (size_t)T_ * HID_);             // 32*1024
    float* srb = slb + B_ * NH_ * D_;
    unsigned int* rmaxkey = (unsigned int*)(srb + B_ * NH_ * D_);  // [2][32]
    unsigned int* bar = (unsigned int*)(base + (40u << 20));

    init_k<<<1, 256, 0, stream>>>(bar);
    mega_k<<<NB_, 256, 0, stream>>>(X_obs, mask, W_in, b_in, gat_W, gat_a,
                                    ln_g, ln_b, W_out, b_out, out,
                                    Ain, hwN, ck, csum, csca, wm, srtb, sig,
                                    hbuf, hbf, Wt_in, Wcat, WtO,
                                    slb, srb, rmaxkey, bar);
}

// Round 8
// 243.705 us; speedup vs baseline: 4.0659x; 4.0659x over previous
//
#include <hip/hip_runtime.h>
#include <hip/hip_bf16.h>

// Problem constants
constexpr int B_   = 8;
constexpr int D_   = 1024;
constexpr int T_   = 512;
constexpr int HID_ = 256;
constexpr int NH_  = 4;
constexpr int NL_  = 2;
constexpr float ALPHA_ = 0.2f;
constexpr float EPS_   = 1e-5f;
constexpr int OUT_ = 64;
constexpr int M_ = B_ * D_;      // 8192 rows
constexpr int DT_ = D_ * T_;     // 524288
constexpr int KIN_ = 2 * T_;     // 1024

typedef __attribute__((ext_vector_type(8))) short short8;   // 8 bf16 (4 VGPRs)
typedef __attribute__((ext_vector_type(4))) float floatx4;  // 4 fp32 acc

__device__ __forceinline__ unsigned short f2bf(float f) {
    unsigned int u = __float_as_uint(f);
    unsigned int r = u + 0x7fffu + ((u >> 16) & 1u);   // round-to-nearest-even
    return (unsigned short)(r >> 16);
}
// monotone float<->uint key for atomicMax on signed floats
__device__ __forceinline__ unsigned int kenc(float f) {
    unsigned int u = __float_as_uint(f);
    return (u & 0x80000000u) ? ~u : (u | 0x80000000u);
}
__device__ __forceinline__ float kdec(unsigned int k) {
    unsigned int u = (k & 0x80000000u) ? (k ^ 0x80000000u) : ~k;
    return __uint_as_float(u);
}

// ---------------------------------------------------------------------------
// 1) Fused prep: blocks [0,512): imputation -> Ain bf16 [M][1024]=[X_mean|mask]
//    blocks [512,2560): weight transpose/convert + rmaxkey init
// ---------------------------------------------------------------------------
__global__ __launch_bounds__(256) void prep_k(const float* __restrict__ X,
                                              const float* __restrict__ Mk,
                                              const float* __restrict__ W_in,
                                              const float* __restrict__ gatW,
                                              const float* __restrict__ W_out,
                                              unsigned short* __restrict__ Ain,
                                              unsigned short* __restrict__ Wt_in,
                                              unsigned short* __restrict__ Wcat,
                                              unsigned short* __restrict__ WtO,
                                              unsigned int* __restrict__ rmaxkey) {
    int bx = blockIdx.x;
    if (bx < 512) {
        int idx4 = (bx * 256 + threadIdx.x) * 4;   // over D*T
        int t = idx4 & (T_ - 1);
        int d = idx4 >> 9;
        float4 x[B_], m[B_];
        float4 s = {0, 0, 0, 0}, c = {0, 0, 0, 0};
#pragma unroll
        for (int b = 0; b < B_; b++) {
            x[b] = *(const float4*)&X[(size_t)b * DT_ + idx4];
            m[b] = *(const float4*)&Mk[(size_t)b * DT_ + idx4];
            s.x += x[b].x * m[b].x; s.y += x[b].y * m[b].y;
            s.z += x[b].z * m[b].z; s.w += x[b].w * m[b].w;
            c.x += m[b].x; c.y += m[b].y; c.z += m[b].z; c.w += m[b].w;
        }
        float4 pm;
        pm.x = s.x / (c.x + 1e-10f); pm.y = s.y / (c.y + 1e-10f);
        pm.z = s.z / (c.z + 1e-10f); pm.w = s.w / (c.w + 1e-10f);
#pragma unroll
        for (int b = 0; b < B_; b++) {
            size_t row = (size_t)b * D_ + d;
            ushort4 xm, mk;
            xm.x = f2bf(x[b].x * m[b].x + (1.f - m[b].x) * pm.x);
            xm.y = f2bf(x[b].y * m[b].y + (1.f - m[b].y) * pm.y);
            xm.z = f2bf(x[b].z * m[b].z + (1.f - m[b].z) * pm.z);
            xm.w = f2bf(x[b].w * m[b].w + (1.f - m[b].w) * pm.w);
            mk.x = f2bf(m[b].x); mk.y = f2bf(m[b].y);
            mk.z = f2bf(m[b].z); mk.w = f2bf(m[b].w);
            *(ushort4*)&Ain[row * KIN_ + t]      = xm;
            *(ushort4*)&Ain[row * KIN_ + T_ + t] = mk;
        }
    } else {
        int idx = (bx - 512) * 256 + threadIdx.x;
        if (idx < 64) rmaxkey[idx] = 0u;
        if (idx < 262144) {
            int n = idx >> 10, k = idx & 1023;     // Wt_in[n][k] = W_in[k][n]
            Wt_in[idx] = f2bf(W_in[(size_t)k * HID_ + n]);
        } else if (idx < 393216) {
            int j = idx - 262144;
            int l = j >> 16, n = (j >> 8) & 255, k = j & 255;
            int h = n >> 6, e = n & 63;
            Wcat[j] = f2bf(gatW[(((size_t)(l * NH_ + h) * HID_) + k) * OUT_ + e]);
        } else {
            int j = idx - 393216;
            int n = j >> 8, k = j & 255;           // WtO[n][k] = W_out[k][n]
            WtO[j] = f2bf(W_out[(size_t)k * T_ + n]);
        }
    }
}

// ---------------------------------------------------------------------------
// 2) bf16 MFMA GEMM (r0-proven). BM=64 BN=64 BK=64, 4 waves.
//    MODE 1: fp32 C (+bias) + bf16 copy. MODE 2: hwT[bh][e][m] + s_l/s_r/rmax.
// ---------------------------------------------------------------------------
template <int MODE>
__global__ __launch_bounds__(256) void gemm_bf16_k(
        const unsigned short* __restrict__ A,    // M x K bf16
        const unsigned short* __restrict__ Bt,   // N x K bf16 (B transposed)
        const float* __restrict__ bias,
        float* __restrict__ C,
        unsigned short* __restrict__ Cb,         // bf16 copy (MODE1) / hwT (MODE2)
        const float* __restrict__ ga,
        float* __restrict__ s_l,
        float* __restrict__ s_r,
        unsigned int* __restrict__ rmaxkey,
        int Nsz, int Ksz) {
    __shared__ __align__(16) unsigned short As[2][64 * 72];  // 18 KB, padded
    __shared__ __align__(16) unsigned short Bs[2][64 * 72];  // 18 KB
    int tid = threadIdx.x;
    int wave = tid >> 6, lane = tid & 63;
    int q = lane >> 4, r16 = lane & 15;
    int rowbase = blockIdx.y * 64;
    int colbase = blockIdx.x * 64;

    int srow = tid >> 3, sk = (tid & 7) * 8;
    const unsigned short* Ap0 = A + (size_t)(rowbase + srow) * Ksz + sk;
    const unsigned short* Ap1 = A + (size_t)(rowbase + srow + 32) * Ksz + sk;
    const unsigned short* Bp0 = Bt + (size_t)(colbase + srow) * Ksz + sk;
    const unsigned short* Bp1 = Bt + (size_t)(colbase + srow + 32) * Ksz + sk;
    int la0 = srow * 72 + sk, la1 = (srow + 32) * 72 + sk;

    floatx4 acc[4];
#pragma unroll
    for (int i = 0; i < 4; i++) acc[i] = (floatx4)0.f;

    uint4 pa0 = *(const uint4*)Ap0, pa1 = *(const uint4*)Ap1;
    uint4 pb0 = *(const uint4*)Bp0, pb1 = *(const uint4*)Bp1;
    *(uint4*)&As[0][la0] = pa0;
    *(uint4*)&As[0][la1] = pa1;
    *(uint4*)&Bs[0][la0] = pb0;
    *(uint4*)&Bs[0][la1] = pb1;

    int nk = Ksz >> 6;
    for (int it = 0; it < nk; it++) {
        int cur = it & 1;
        __syncthreads();
        if (it + 1 < nk) {
            int kt = (it + 1) << 6;
            pa0 = *(const uint4*)(Ap0 + kt);
            pa1 = *(const uint4*)(Ap1 + kt);
            pb0 = *(const uint4*)(Bp0 + kt);
            pb1 = *(const uint4*)(Bp1 + kt);
        }
#pragma unroll
        for (int t = 0; t < 2; t++) {
            short8 a = *(const short8*)&As[cur][(wave * 16 + r16) * 72 + t * 32 + q * 8];
#pragma unroll
            for (int ni = 0; ni < 4; ni++) {
                short8 b = *(const short8*)&Bs[cur][(ni * 16 + r16) * 72 + t * 32 + q * 8];
                acc[ni] = __builtin_amdgcn_mfma_f32_16x16x32_bf16(a, b, acc[ni], 0, 0, 0);
            }
        }
        if (it + 1 < nk) {
            int nxt = cur ^ 1;
            *(uint4*)&As[nxt][la0] = pa0;
            *(uint4*)&As[nxt][la1] = pa1;
            *(uint4*)&Bs[nxt][la0] = pb0;
            *(uint4*)&Bs[nxt][la1] = pb1;
        }
    }
    // ---- epilogue. C/D map: col=lane&15, row=(lane>>4)*4+reg ----
    if constexpr (MODE == 2) {
        int bhh = ((rowbase >> 10) << 2) + blockIdx.x;   // b*4 + h
        int nb = (rowbase & (D_ - 1)) + wave * 16;
        // hwT[bh][e][m] bf16 (r0-proven layout for attn Vt staging)
#pragma unroll
        for (int ni = 0; ni < 4; ni++) {
            int e = ni * 16 + r16;
            ushort4 pk;
            pk.x = f2bf(acc[ni][0]);
            pk.y = f2bf(acc[ni][1]);
            pk.z = f2bf(acc[ni][2]);
            pk.w = f2bf(acc[ni][3]);
            *(ushort4*)&Cb[((size_t)(bhh * 64 + e) << 10) + nb + q * 4] = pk;
        }
        // fused s_l/s_r from fp32 acc
        const float* gab = ga + blockIdx.x * 2 * OUT_;
        float al4[4], ar4[4];
#pragma unroll
        for (int ni = 0; ni < 4; ni++) {
            al4[ni] = gab[ni * 16 + r16];
            ar4[ni] = gab[OUT_ + ni * 16 + r16];
        }
        float slv[4], srv[4];
#pragma unroll
        for (int rr = 0; rr < 4; rr++) {
            float s1 = 0.f, s2 = 0.f;
#pragma unroll
            for (int ni = 0; ni < 4; ni++) {
                s1 += acc[ni][rr] * al4[ni];
                s2 += acc[ni][rr] * ar4[ni];
            }
            slv[rr] = s1;
            srv[rr] = s2;
        }
#pragma unroll
        for (int off = 1; off < 16; off <<= 1) {
#pragma unroll
            for (int rr = 0; rr < 4; rr++) {
                slv[rr] += __shfl_xor(slv[rr], off, 64);
                srv[rr] += __shfl_xor(srv[rr], off, 64);
            }
        }
        {
            int rsel = r16 & 3;
            float sv = (rsel == 0) ? slv[0] : (rsel == 1) ? slv[1] : (rsel == 2) ? slv[2] : slv[3];
            float rv = (rsel == 0) ? srv[0] : (rsel == 1) ? srv[1] : (rsel == 2) ? srv[2] : srv[3];
            int n = nb + q * 4 + rsel;
            if (r16 < 4)                 s_l[bhh * D_ + n] = sv;
            else if (r16 >= 8 && r16 < 12) s_r[bhh * D_ + n] = rv;
        }
        float mx = fmaxf(fmaxf(srv[0], srv[1]), fmaxf(srv[2], srv[3]));
        mx = fmaxf(mx, __shfl_xor(mx, 16, 64));
        mx = fmaxf(mx, __shfl_xor(mx, 32, 64));
        if (lane == 0) atomicMax(&rmaxkey[bhh], kenc(mx));
    } else {
#pragma unroll
        for (int rr = 0; rr < 4; rr++) {
            int row = rowbase + wave * 16 + q * 4 + rr;
#pragma unroll
            for (int ni = 0; ni < 4; ni++) {
                int col = colbase + ni * 16 + r16;
                float v = acc[ni][rr] + (bias ? bias[col] : 0.f);
                C[(size_t)row * Nsz + col] = v;
                if constexpr (MODE == 1) Cb[(size_t)row * Nsz + col] = f2bf(v);
            }
        }
    }
}

// ---------------------------------------------------------------------------
// 3) Attention via MFMA, full-m (no split). grid (32 bh, 16 rowblocks),
//    256 thr, 4 waves; 8 chunks of 128 m, Vt ping-pong. Normalizes in-kernel
//    and writes hnew[b][n][h*64+e] fp32 (no pacc/pden round-trip).
// ---------------------------------------------------------------------------
__global__ __launch_bounds__(256) void attn_k(const unsigned short* __restrict__ hwT,
                                              const float* __restrict__ sl_g,
                                              const float* __restrict__ sr_g,
                                              const unsigned int* __restrict__ rmaxkey,
                                              float* __restrict__ hnew) {
    int bh = blockIdx.x;
    int b = bh >> 2, h = bh & 3;
    int tid = threadIdx.x;
    int wave = tid >> 6, lane = tid & 63;
    int q = lane >> 4, r16 = lane & 15;

    __shared__ float srs[1024];                               // 4 KB
    __shared__ __align__(16) unsigned short Vt[2][64][136];   // 34 KB ping-pong

    *(float4*)&srs[tid * 4] = *(const float4*)&sr_g[bh * D_ + tid * 4];

    float rm = kdec(rmaxkey[bh]);
    int row0 = blockIdx.y * 64 + wave * 16;
    float sl = sl_g[bh * D_ + row0 + r16];
    float xm = sl + rm;
    float Mn = fmaxf(xm, ALPHA_ * xm);            // = max_m e[n,m]

    floatx4 acc[4];
#pragma unroll
    for (int i = 0; i < 4; i++) acc[i] = (floatx4)0.f;
    float dsum = 0.f;

    const unsigned short* vbase = hwT + ((size_t)(bh * 64) << 10);
    int se[4], sp[4];
#pragma unroll
    for (int i = 0; i < 4; i++) {
        int s = tid + i * 256;
        se[i] = s >> 4;
        sp[i] = (s & 15) * 8;
    }

    uint4 pre[4];
#pragma unroll
    for (int i = 0; i < 4; i++)
        pre[i] = *(const uint4*)&vbase[((size_t)se[i] << 10) + sp[i]];
#pragma unroll
    for (int i = 0; i < 4; i++)
        *(uint4*)&Vt[0][se[i]][sp[i]] = pre[i];
    __syncthreads();   // covers srs + buffer 0

    for (int c = 0; c < 8; c++) {
        int cur = c & 1;
        if (c < 7) {
            int mo = (c + 1) * 128;
#pragma unroll
            for (int i = 0; i < 4; i++)
                pre[i] = *(const uint4*)&vbase[((size_t)se[i] << 10) + mo + sp[i]];
        }
#pragma unroll
        for (int kk = 0; kk < 128; kk += 32) {
            int m0 = c * 128 + kk + q * 8;
            float4 s0 = *(const float4*)&srs[m0];
            float4 s1 = *(const float4*)&srs[m0 + 4];
            float sr8[8] = {s0.x, s0.y, s0.z, s0.w, s1.x, s1.y, s1.z, s1.w};
            float p[8];
#pragma unroll
            for (int j = 0; j < 8; j++) {
                float x = sl + sr8[j];
                float e = fmaxf(x, ALPHA_ * x);
                float pj = __expf(e - Mn);
                dsum += pj;
                p[j] = pj;
            }
            union { unsigned int u[4]; short8 s8; } cv;
#pragma unroll
            for (int j = 0; j < 4; j++) {
                unsigned int lo = (__float_as_uint(p[2 * j]) + 0x8000u) >> 16;
                unsigned int hi = (__float_as_uint(p[2 * j + 1]) + 0x8000u) & 0xffff0000u;
                cv.u[j] = hi | lo;
            }
#pragma unroll
            for (int ni = 0; ni < 4; ni++) {
                short8 bfr = *(const short8*)&Vt[cur][ni * 16 + r16][kk + q * 8];
                acc[ni] = __builtin_amdgcn_mfma_f32_16x16x32_bf16(cv.s8, bfr, acc[ni], 0, 0, 0);
            }
        }
        if (c < 7) {
#pragma unroll
            for (int i = 0; i < 4; i++)
                *(uint4*)&Vt[cur ^ 1][se[i]][sp[i]] = pre[i];
        }
        __syncthreads();
    }
    dsum += __shfl_xor(dsum, 16);
    dsum += __shfl_xor(dsum, 32);     // now per-r16 total for row row0+r16
#pragma unroll
    for (int rr = 0; rr < 4; rr++) {
        float inv = 1.f / __shfl(dsum, q * 4 + rr, 64);   // D rows are q*4+rr
        size_t off = ((size_t)(b * D_ + row0 + q * 4 + rr)) * HID_ + h * OUT_;
#pragma unroll
        for (int ni = 0; ni < 4; ni++)
            hnew[off + ni * 16 + r16] = acc[ni][rr] * inv;
    }
}

// ---------------------------------------------------------------------------
// 4) gemmln_k: fused {residual + LayerNorm} prologue -> static-A LDS (K=256)
//    -> MFMA GEMM. LN output written to hout (fp32) by bx==0 only (race-free
//    via hbufA/hbufB ping-pong). MODE 2: hwT + s_l/s_r/rmax. MODE 0: C+bias.
// ---------------------------------------------------------------------------
template <int MODE>
__global__ __launch_bounds__(256) void gemmln_k(
        const float* __restrict__ hbase,         // M x 256 fp32 residual
        const float* __restrict__ hnewIn,        // M x 256 fp32 attn out
        const float* __restrict__ lng,
        const float* __restrict__ lnb,
        float* __restrict__ hout,                // M x 256 fp32 or null
        const unsigned short* __restrict__ Bt,   // N x 256 bf16
        const float* __restrict__ bias,          // MODE 0
        float* __restrict__ C,                   // MODE 0
        unsigned short* __restrict__ Cb,         // MODE 2 hwT
        const float* __restrict__ ga,
        float* __restrict__ s_l,
        float* __restrict__ s_r,
        unsigned int* __restrict__ rmaxkey,
        int Nsz) {
    __shared__ __align__(16) unsigned short Asf[64 * 264];    // 33.8 KB static A
    __shared__ __align__(16) unsigned short Bs[2][64 * 72];   // 18.4 KB
    int tid = threadIdx.x;
    int wave = tid >> 6, lane = tid & 63;
    int q = lane >> 4, r16 = lane & 15;
    int rowbase = blockIdx.y * 64;
    int colbase = blockIdx.x * 64;

    // ---- LN prologue: wave w handles rows w*16..w*16+15, lane = col/4 ----
    {
        float4 gg = *(const float4*)&lng[lane * 4];
        float4 bv = *(const float4*)&lnb[lane * 4];
        for (int rr = 0; rr < 16; ++rr) {
            int row = wave * 16 + rr;
            size_t grow = (size_t)(rowbase + row) * HID_ + lane * 4;
            float4 a  = *(const float4*)&hbase[grow];
            float4 nv = *(const float4*)&hnewIn[grow];
            float4 v = {a.x + nv.x, a.y + nv.y, a.z + nv.z, a.w + nv.w};
            float s = v.x + v.y + v.z + v.w;
#pragma unroll
            for (int off = 1; off < 64; off <<= 1) s += __shfl_xor(s, off, 64);
            float mu = s * (1.f / HID_);
            float4 dd = {v.x - mu, v.y - mu, v.z - mu, v.w - mu};
            float s2 = dd.x * dd.x + dd.y * dd.y + dd.z * dd.z + dd.w * dd.w;
#pragma unroll
            for (int off = 1; off < 64; off <<= 1) s2 += __shfl_xor(s2, off, 64);
            float rs = rsqrtf(s2 * (1.f / HID_) + EPS_);
            float4 res;
            res.x = dd.x * rs * gg.x + bv.x;
            res.y = dd.y * rs * gg.y + bv.y;
            res.z = dd.z * rs * gg.z + bv.z;
            res.w = dd.w * rs * gg.w + bv.w;
            if (hout && blockIdx.x == 0) *(float4*)&hout[grow] = res;
            ushort4 pk = {f2bf(res.x), f2bf(res.y), f2bf(res.z), f2bf(res.w)};
            *(ushort4*)&Asf[row * 264 + lane * 4] = pk;
        }
    }
    // ---- stage B tile 0 ----
    int srow = tid >> 3, sk = (tid & 7) * 8;
    const unsigned short* Bp0 = Bt + (size_t)(colbase + srow) * HID_ + sk;
    const unsigned short* Bp1 = Bt + (size_t)(colbase + srow + 32) * HID_ + sk;
    int la0 = srow * 72 + sk, la1 = (srow + 32) * 72 + sk;
    uint4 pb0 = *(const uint4*)Bp0, pb1 = *(const uint4*)Bp1;
    *(uint4*)&Bs[0][la0] = pb0;
    *(uint4*)&Bs[0][la1] = pb1;
    __syncthreads();   // covers Asf + Bs[0]

    floatx4 acc[4];
#pragma unroll
    for (int i = 0; i < 4; i++) acc[i] = (floatx4)0.f;

    constexpr int nk = HID_ / 64;   // 4
    for (int it = 0; it < nk; it++) {
        int cur = it & 1;
        if (it + 1 < nk) {
            int kt = (it + 1) << 6;
            pb0 = *(const uint4*)(Bp0 + kt);
            pb1 = *(const uint4*)(Bp1 + kt);
        }
#pragma unroll
        for (int t = 0; t < 2; t++) {
            short8 a = *(const short8*)&Asf[(wave * 16 + r16) * 264 + it * 64 + t * 32 + q * 8];
#pragma unroll
            for (int ni = 0; ni < 4; ni++) {
                short8 b = *(const short8*)&Bs[cur][(ni * 16 + r16) * 72 + t * 32 + q * 8];
                acc[ni] = __builtin_amdgcn_mfma_f32_16x16x32_bf16(a, b, acc[ni], 0, 0, 0);
            }
        }
        if (it + 1 < nk) {
            int nxt = cur ^ 1;
            *(uint4*)&Bs[nxt][la0] = pb0;
            *(uint4*)&Bs[nxt][la1] = pb1;
        }
        __syncthreads();
    }
    // ---- epilogues (identical to gemm_bf16_k) ----
    if constexpr (MODE == 2) {
        int bhh = ((rowbase >> 10) << 2) + blockIdx.x;
        int nb = (rowbase & (D_ - 1)) + wave * 16;
#pragma unroll
        for (int ni = 0; ni < 4; ni++) {
            int e = ni * 16 + r16;
            ushort4 pk;
            pk.x = f2bf(acc[ni][0]);
            pk.y = f2bf(acc[ni][1]);
            pk.z = f2bf(acc[ni][2]);
            pk.w = f2bf(acc[ni][3]);
            *(ushort4*)&Cb[((size_t)(bhh * 64 + e) << 10) + nb + q * 4] = pk;
        }
        const float* gab = ga + blockIdx.x * 2 * OUT_;
        float al4[4], ar4[4];
#pragma unroll
        for (int ni = 0; ni < 4; ni++) {
            al4[ni] = gab[ni * 16 + r16];
            ar4[ni] = gab[OUT_ + ni * 16 + r16];
        }
        float slv[4], srv[4];
#pragma unroll
        for (int rr = 0; rr < 4; rr++) {
            float s1 = 0.f, s2 = 0.f;
#pragma unroll
            for (int ni = 0; ni < 4; ni++) {
                s1 += acc[ni][rr] * al4[ni];
                s2 += acc[ni][rr] * ar4[ni];
            }
            slv[rr] = s1;
            srv[rr] = s2;
        }
#pragma unroll
        for (int off = 1; off < 16; off <<= 1) {
#pragma unroll
            for (int rr = 0; rr < 4; rr++) {
                slv[rr] += __shfl_xor(slv[rr], off, 64);
                srv[rr] += __shfl_xor(srv[rr], off, 64);
            }
        }
        {
            int rsel = r16 & 3;
            float sv = (rsel == 0) ? slv[0] : (rsel == 1) ? slv[1] : (rsel == 2) ? slv[2] : slv[3];
            float rv = (rsel == 0) ? srv[0] : (rsel == 1) ? srv[1] : (rsel == 2) ? srv[2] : srv[3];
            int n = nb + q * 4 + rsel;
            if (r16 < 4)                 s_l[bhh * D_ + n] = sv;
            else if (r16 >= 8 && r16 < 12) s_r[bhh * D_ + n] = rv;
        }
        float mx = fmaxf(fmaxf(srv[0], srv[1]), fmaxf(srv[2], srv[3]));
        mx = fmaxf(mx, __shfl_xor(mx, 16, 64));
        mx = fmaxf(mx, __shfl_xor(mx, 32, 64));
        if (lane == 0) atomicMax(&rmaxkey[bhh], kenc(mx));
    } else {
#pragma unroll
        for (int rr = 0; rr < 4; rr++) {
            int row = rowbase + wave * 16 + q * 4 + rr;
#pragma unroll
            for (int ni = 0; ni < 4; ni++) {
                int col = colbase + ni * 16 + r16;
                C[(size_t)row * Nsz + col] = acc[ni][rr] + bias[col];
            }
        }
    }
}

// ---------------------------------------------------------------------------
extern "C" void kernel_launch(void* const* d_in, const int* in_sizes, int n_in,
                              void* d_out, int out_size, void* d_ws, size_t ws_size,
                              hipStream_t stream) {
    const float* X_obs = (const float*)d_in[0];
    const float* mask  = (const float*)d_in[1];
    const float* W_in  = (const float*)d_in[2];
    const float* b_in  = (const float*)d_in[3];
    const float* gat_W = (const float*)d_in[4];
    const float* gat_a = (const float*)d_in[5];
    const float* ln_g  = (const float*)d_in[6];
    const float* ln_b  = (const float*)d_in[7];
    const float* W_out = (const float*)d_in[8];
    const float* b_out = (const float*)d_in[9];
    float* out = (float*)d_out;

    // Workspace layout:
    //  [0,16M):   Ain bf16 (M x 1024), dead after gemm1; hwT bf16 [32][64][1024]
    //             overlays [0,4M); hnew0 fp32 [M][256] at [4,12M);
    //             hnew1 fp32 at [12,20M)
    //  [21M,29M): hbufA fp32 (M x 256)
    //  [29M,33M): hbf bf16 (M x 256)
    //  [33M,41M): hbufB fp32 (M x 256)
    //  [42M,+):   Wt_in, Wcat, WtO (bf16), slb/srb (fp32), rmaxkey (uint[64])
    char* base = (char*)d_ws;
    unsigned short* Ain  = (unsigned short*)base;
    unsigned short* hwT  = (unsigned short*)base;
    float* hnew0 = (float*)(base + (4u << 20));
    float* hnew1 = (float*)(base + (12u << 20));
    float* hbufA = (float*)(base + (21u << 20));
    unsigned short* hbf   = (unsigned short*)(base + (29u << 20));
    float* hbufB = (float*)(base + (33u << 20));
    unsigned short* Wt_in = (unsigned short*)(base + (42u << 20));
    unsigned short* Wcat  = Wt_in + (size_t)HID_ * KIN_;        // 256*1024
    unsigned short* WtO   = Wcat + (size_t)NL_ * HID_ * HID_;   // 2*256*256
    float* slb = (float*)(WtO + (size_t)T_ * HID_);             // 32*1024
    float* srb = slb + B_ * NH_ * D_;
    unsigned int* rmaxkey = (unsigned int*)(srb + B_ * NH_ * D_);  // [2][32]

    prep_k<<<2560, 256, 0, stream>>>(X_obs, mask, W_in, gat_W, W_out,
                                     Ain, Wt_in, Wcat, WtO, rmaxkey);

    // h0 = [X_mean|mask] @ W_in + b_in -> hbufA fp32 + hbf bf16
    gemm_bf16_k<1><<<dim3(HID_ / 64, M_ / 64), 256, 0, stream>>>(
        Ain, Wt_in, b_in, hbufA, hbf, nullptr, nullptr, nullptr, nullptr,
        HID_, KIN_);

    // layer 0: hW = h0 @ W0 -> hwT + s_l/s_r/rmax ; attn -> hnew0
    gemm_bf16_k<2><<<dim3(HID_ / 64, M_ / 64), 256, 0, stream>>>(
        hbf, Wcat, nullptr, nullptr, hwT,
        gat_a, slb, srb, rmaxkey, HID_, HID_);
    attn_k<<<dim3(B_ * NH_, D_ / 64), 256, 0, stream>>>(
        hwT, slb, srb, rmaxkey, hnew0);

    // layer 1: fused {h1 = LN(h0 + hnew0)} + gemm2 -> hwT + s_l/s_r/rmax
    gemmln_k<2><<<dim3(HID_ / 64, M_ / 64), 256, 0, stream>>>(
        hbufA, hnew0, ln_g, ln_b, hbufB,
        Wcat + (size_t)HID_ * HID_, nullptr, nullptr, hwT,
        gat_a + (size_t)NH_ * 2 * OUT_, slb, srb, rmaxkey + 32, HID_);
    attn_k<<<dim3(B_ * NH_, D_ / 64), 256, 0, stream>>>(
        hwT, slb, srb, rmaxkey + 32, hnew1);

    // out = LN(h1 + hnew1) @ W_out + b_out  (fused LN prologue)
    gemmln_k<0><<<dim3(T_ / 64, M_ / 64), 256, 0, stream>>>(
        hbufB, hnew1, ln_g + HID_, ln_b + HID_, nullptr,
        WtO, b_out, out, nullptr,
        nullptr, nullptr, nullptr, nullptr, T_);
}

// Round 9
// 237.243 us; speedup vs baseline: 4.1766x; 1.0272x over previous
//
#include <hip/hip_runtime.h>
#include <hip/hip_bf16.h>

// Problem constants
constexpr int B_   = 8;
constexpr int D_   = 1024;
constexpr int T_   = 512;
constexpr int HID_ = 256;
constexpr int NH_  = 4;
constexpr int NL_  = 2;
constexpr float ALPHA_ = 0.2f;
constexpr float EPS_   = 1e-5f;
constexpr int OUT_ = 64;
constexpr int M_ = B_ * D_;      // 8192 rows
constexpr int DT_ = D_ * T_;     // 524288
constexpr int KIN_ = 2 * T_;     // 1024

typedef __attribute__((ext_vector_type(8))) short short8;   // 8 bf16 (4 VGPRs)
typedef __attribute__((ext_vector_type(4))) float floatx4;  // 4 fp32 acc

__device__ __forceinline__ unsigned short f2bf(float f) {
    unsigned int u = __float_as_uint(f);
    unsigned int r = u + 0x7fffu + ((u >> 16) & 1u);   // round-to-nearest-even
    return (unsigned short)(r >> 16);
}
// monotone float<->uint key for atomicMax on signed floats
__device__ __forceinline__ unsigned int kenc(float f) {
    unsigned int u = __float_as_uint(f);
    return (u & 0x80000000u) ? ~u : (u | 0x80000000u);
}
__device__ __forceinline__ float kdec(unsigned int k) {
    unsigned int u = (k & 0x80000000u) ? (k ^ 0x80000000u) : ~k;
    return __uint_as_float(u);
}

// ---------------------------------------------------------------------------
// 1) Fused prep: blocks [0,512): imputation -> Ain bf16 [M][1024]=[X_mean|mask]
//    blocks [512,2560): weight transpose/convert + rmaxkey init
// ---------------------------------------------------------------------------
__global__ __launch_bounds__(256) void prep_k(const float* __restrict__ X,
                                              const float* __restrict__ Mk,
                                              const float* __restrict__ W_in,
                                              const float* __restrict__ gatW,
                                              const float* __restrict__ W_out,
                                              unsigned short* __restrict__ Ain,
                                              unsigned short* __restrict__ Wt_in,
                                              unsigned short* __restrict__ Wcat,
                                              unsigned short* __restrict__ WtO,
                                              unsigned int* __restrict__ rmaxkey) {
    int bx = blockIdx.x;
    if (bx < 512) {
        int idx4 = (bx * 256 + threadIdx.x) * 4;   // over D*T
        int t = idx4 & (T_ - 1);
        int d = idx4 >> 9;
        float4 x[B_], m[B_];
        float4 s = {0, 0, 0, 0}, c = {0, 0, 0, 0};
#pragma unroll
        for (int b = 0; b < B_; b++) {
            x[b] = *(const float4*)&X[(size_t)b * DT_ + idx4];
            m[b] = *(const float4*)&Mk[(size_t)b * DT_ + idx4];
            s.x += x[b].x * m[b].x; s.y += x[b].y * m[b].y;
            s.z += x[b].z * m[b].z; s.w += x[b].w * m[b].w;
            c.x += m[b].x; c.y += m[b].y; c.z += m[b].z; c.w += m[b].w;
        }
        float4 pm;
        pm.x = s.x / (c.x + 1e-10f); pm.y = s.y / (c.y + 1e-10f);
        pm.z = s.z / (c.z + 1e-10f); pm.w = s.w / (c.w + 1e-10f);
#pragma unroll
        for (int b = 0; b < B_; b++) {
            size_t row = (size_t)b * D_ + d;
            ushort4 xm, mk;
            xm.x = f2bf(x[b].x * m[b].x + (1.f - m[b].x) * pm.x);
            xm.y = f2bf(x[b].y * m[b].y + (1.f - m[b].y) * pm.y);
            xm.z = f2bf(x[b].z * m[b].z + (1.f - m[b].z) * pm.z);
            xm.w = f2bf(x[b].w * m[b].w + (1.f - m[b].w) * pm.w);
            mk.x = f2bf(m[b].x); mk.y = f2bf(m[b].y);
            mk.z = f2bf(m[b].z); mk.w = f2bf(m[b].w);
            *(ushort4*)&Ain[row * KIN_ + t]      = xm;
            *(ushort4*)&Ain[row * KIN_ + T_ + t] = mk;
        }
    } else {
        int idx = (bx - 512) * 256 + threadIdx.x;
        if (idx < 64) rmaxkey[idx] = 0u;
        if (idx < 262144) {
            int n = idx >> 10, k = idx & 1023;     // Wt_in[n][k] = W_in[k][n]
            Wt_in[idx] = f2bf(W_in[(size_t)k * HID_ + n]);
        } else if (idx < 393216) {
            int j = idx - 262144;
            int l = j >> 16, n = (j >> 8) & 255, k = j & 255;
            int h = n >> 6, e = n & 63;
            Wcat[j] = f2bf(gatW[(((size_t)(l * NH_ + h) * HID_) + k) * OUT_ + e]);
        } else {
            int j = idx - 393216;
            int n = j >> 8, k = j & 255;           // WtO[n][k] = W_out[k][n]
            WtO[j] = f2bf(W_out[(size_t)k * T_ + n]);
        }
    }
}

// ---------------------------------------------------------------------------
// 2) bf16 MFMA GEMM (r0-proven). BM=64 BN=64 BK=64, 4 waves.
//    MODE 0: fp32 C (+bias). MODE 1: + bf16 copy. MODE 2: hwT + s_l/s_r/rmax.
// ---------------------------------------------------------------------------
template <int MODE>
__global__ __launch_bounds__(256) void gemm_bf16_k(
        const unsigned short* __restrict__ A,    // M x K bf16
        const unsigned short* __restrict__ Bt,   // N x K bf16 (B transposed)
        const float* __restrict__ bias,
        float* __restrict__ C,
        unsigned short* __restrict__ Cb,         // bf16 copy (MODE1) / hwT (MODE2)
        const float* __restrict__ ga,
        float* __restrict__ s_l,
        float* __restrict__ s_r,
        unsigned int* __restrict__ rmaxkey,
        int Nsz, int Ksz) {
    __shared__ __align__(16) unsigned short As[2][64 * 72];  // 18 KB, padded
    __shared__ __align__(16) unsigned short Bs[2][64 * 72];  // 18 KB
    int tid = threadIdx.x;
    int wave = tid >> 6, lane = tid & 63;
    int q = lane >> 4, r16 = lane & 15;
    int rowbase = blockIdx.y * 64;
    int colbase = blockIdx.x * 64;

    int srow = tid >> 3, sk = (tid & 7) * 8;
    const unsigned short* Ap0 = A + (size_t)(rowbase + srow) * Ksz + sk;
    const unsigned short* Ap1 = A + (size_t)(rowbase + srow + 32) * Ksz + sk;
    const unsigned short* Bp0 = Bt + (size_t)(colbase + srow) * Ksz + sk;
    const unsigned short* Bp1 = Bt + (size_t)(colbase + srow + 32) * Ksz + sk;
    int la0 = srow * 72 + sk, la1 = (srow + 32) * 72 + sk;

    floatx4 acc[4];
#pragma unroll
    for (int i = 0; i < 4; i++) acc[i] = (floatx4)0.f;

    uint4 pa0 = *(const uint4*)Ap0, pa1 = *(const uint4*)Ap1;
    uint4 pb0 = *(const uint4*)Bp0, pb1 = *(const uint4*)Bp1;
    *(uint4*)&As[0][la0] = pa0;
    *(uint4*)&As[0][la1] = pa1;
    *(uint4*)&Bs[0][la0] = pb0;
    *(uint4*)&Bs[0][la1] = pb1;

    int nk = Ksz >> 6;
    for (int it = 0; it < nk; it++) {
        int cur = it & 1;
        __syncthreads();
        if (it + 1 < nk) {
            int kt = (it + 1) << 6;
            pa0 = *(const uint4*)(Ap0 + kt);
            pa1 = *(const uint4*)(Ap1 + kt);
            pb0 = *(const uint4*)(Bp0 + kt);
            pb1 = *(const uint4*)(Bp1 + kt);
        }
#pragma unroll
        for (int t = 0; t < 2; t++) {
            short8 a = *(const short8*)&As[cur][(wave * 16 + r16) * 72 + t * 32 + q * 8];
#pragma unroll
            for (int ni = 0; ni < 4; ni++) {
                short8 b = *(const short8*)&Bs[cur][(ni * 16 + r16) * 72 + t * 32 + q * 8];
                acc[ni] = __builtin_amdgcn_mfma_f32_16x16x32_bf16(a, b, acc[ni], 0, 0, 0);
            }
        }
        if (it + 1 < nk) {
            int nxt = cur ^ 1;
            *(uint4*)&As[nxt][la0] = pa0;
            *(uint4*)&As[nxt][la1] = pa1;
            *(uint4*)&Bs[nxt][la0] = pb0;
            *(uint4*)&Bs[nxt][la1] = pb1;
        }
    }
    // ---- epilogue. C/D map: col=lane&15, row=(lane>>4)*4+reg ----
    if constexpr (MODE == 2) {
        int bhh = ((rowbase >> 10) << 2) + blockIdx.x;   // b*4 + h
        int nb = (rowbase & (D_ - 1)) + wave * 16;
        // hwT[bh][e][m] bf16
#pragma unroll
        for (int ni = 0; ni < 4; ni++) {
            int e = ni * 16 + r16;
            ushort4 pk;
            pk.x = f2bf(acc[ni][0]);
            pk.y = f2bf(acc[ni][1]);
            pk.z = f2bf(acc[ni][2]);
            pk.w = f2bf(acc[ni][3]);
            *(ushort4*)&Cb[((size_t)(bhh * 64 + e) << 10) + nb + q * 4] = pk;
        }
        // fused s_l/s_r from fp32 acc
        const float* gab = ga + blockIdx.x * 2 * OUT_;
        float al4[4], ar4[4];
#pragma unroll
        for (int ni = 0; ni < 4; ni++) {
            al4[ni] = gab[ni * 16 + r16];
            ar4[ni] = gab[OUT_ + ni * 16 + r16];
        }
        float slv[4], srv[4];
#pragma unroll
        for (int rr = 0; rr < 4; rr++) {
            float s1 = 0.f, s2 = 0.f;
#pragma unroll
            for (int ni = 0; ni < 4; ni++) {
                s1 += acc[ni][rr] * al4[ni];
                s2 += acc[ni][rr] * ar4[ni];
            }
            slv[rr] = s1;
            srv[rr] = s2;
        }
#pragma unroll
        for (int off = 1; off < 16; off <<= 1) {
#pragma unroll
            for (int rr = 0; rr < 4; rr++) {
                slv[rr] += __shfl_xor(slv[rr], off, 64);
                srv[rr] += __shfl_xor(srv[rr], off, 64);
            }
        }
        {
            int rsel = r16 & 3;
            float sv = (rsel == 0) ? slv[0] : (rsel == 1) ? slv[1] : (rsel == 2) ? slv[2] : slv[3];
            float rv = (rsel == 0) ? srv[0] : (rsel == 1) ? srv[1] : (rsel == 2) ? srv[2] : srv[3];
            int n = nb + q * 4 + rsel;
            if (r16 < 4)                 s_l[bhh * D_ + n] = sv;
            else if (r16 >= 8 && r16 < 12) s_r[bhh * D_ + n] = rv;
        }
        float mx = fmaxf(fmaxf(srv[0], srv[1]), fmaxf(srv[2], srv[3]));
        mx = fmaxf(mx, __shfl_xor(mx, 16, 64));
        mx = fmaxf(mx, __shfl_xor(mx, 32, 64));
        if (lane == 0) atomicMax(&rmaxkey[bhh], kenc(mx));
    } else {
#pragma unroll
        for (int rr = 0; rr < 4; rr++) {
            int row = rowbase + wave * 16 + q * 4 + rr;
#pragma unroll
            for (int ni = 0; ni < 4; ni++) {
                int col = colbase + ni * 16 + r16;
                float v = acc[ni][rr] + (bias ? bias[col] : 0.f);
                C[(size_t)row * Nsz + col] = v;
                if constexpr (MODE == 1) Cb[(size_t)row * Nsz + col] = f2bf(v);
            }
        }
    }
}

// ---------------------------------------------------------------------------
// 3) Attention via MFMA, split-e. grid (32 bh, 16 rowblocks, 2 e-halves),
//    256 thr, 4 waves; each block sweeps ALL m for 32 e-columns => full dsum
//    per block => normalize in-kernel, write hnew directly (no pacc/pden).
//    sl/sr pre-scaled by log2e so the inner loop uses native exp2f.
// ---------------------------------------------------------------------------
__global__ __launch_bounds__(256) void attn_k(const unsigned short* __restrict__ hwT,
                                              const float* __restrict__ sl_g,
                                              const float* __restrict__ sr_g,
                                              const unsigned int* __restrict__ rmaxkey,
                                              float* __restrict__ hnew) {
    int bh = blockIdx.x;
    int b = bh >> 2, h = bh & 3;
    int eh = blockIdx.z;
    int tid = threadIdx.x;
    int wave = tid >> 6, lane = tid & 63;
    int q = lane >> 4, r16 = lane & 15;

    __shared__ float srs[1024];                               // 4 KB (scaled by log2e)
    __shared__ __align__(16) unsigned short Vt[2][32][136];   // 17.4 KB ping-pong

    constexpr float L2E = 1.4426950408889634f;
    {
        float4 v = *(const float4*)&sr_g[bh * D_ + tid * 4];
        v.x *= L2E; v.y *= L2E; v.z *= L2E; v.w *= L2E;
        *(float4*)&srs[tid * 4] = v;
    }

    float rm = kdec(rmaxkey[bh]) * L2E;
    int row0 = blockIdx.y * 64 + wave * 16;
    float sl = sl_g[bh * D_ + row0 + r16] * L2E;
    float xm = sl + rm;
    float Mn = fmaxf(xm, ALPHA_ * xm);            // = log2-scaled max_m e[n,m]

    floatx4 acc[2];
    acc[0] = (floatx4)0.f;
    acc[1] = (floatx4)0.f;
    float dsum = 0.f;

    const unsigned short* vbase = hwT + ((size_t)(bh * 64 + eh * 32) << 10);
    int se[2], sp[2];
#pragma unroll
    for (int i = 0; i < 2; i++) {
        int s = tid + i * 256;
        se[i] = s >> 4;
        sp[i] = (s & 15) * 8;
    }

    uint4 pre[2];
#pragma unroll
    for (int i = 0; i < 2; i++)
        pre[i] = *(const uint4*)&vbase[((size_t)se[i] << 10) + sp[i]];
#pragma unroll
    for (int i = 0; i < 2; i++)
        *(uint4*)&Vt[0][se[i]][sp[i]] = pre[i];
    __syncthreads();   // covers srs + buffer 0

    for (int c = 0; c < 8; c++) {
        int cur = c & 1;
        if (c < 7) {
            int mo = (c + 1) * 128;
#pragma unroll
            for (int i = 0; i < 2; i++)
                pre[i] = *(const uint4*)&vbase[((size_t)se[i] << 10) + mo + sp[i]];
        }
#pragma unroll
        for (int kk = 0; kk < 128; kk += 32) {
            int m0 = c * 128 + kk + q * 8;
            float4 s0 = *(const float4*)&srs[m0];
            float4 s1 = *(const float4*)&srs[m0 + 4];
            float sr8[8] = {s0.x, s0.y, s0.z, s0.w, s1.x, s1.y, s1.z, s1.w};
            float p[8];
#pragma unroll
            for (int j = 0; j < 8; j++) {
                float x = sl + sr8[j];
                float e = fmaxf(x, ALPHA_ * x);
                float pj = exp2f(e - Mn);
                dsum += pj;
                p[j] = pj;
            }
            union { unsigned int u[4]; short8 s8; } cv;
#pragma unroll
            for (int j = 0; j < 4; j++) {
                unsigned int lo = (__float_as_uint(p[2 * j]) + 0x8000u) >> 16;
                unsigned int hi = (__float_as_uint(p[2 * j + 1]) + 0x8000u) & 0xffff0000u;
                cv.u[j] = hi | lo;
            }
#pragma unroll
            for (int ni = 0; ni < 2; ni++) {
                short8 bfr = *(const short8*)&Vt[cur][ni * 16 + r16][kk + q * 8];
                acc[ni] = __builtin_amdgcn_mfma_f32_16x16x32_bf16(cv.s8, bfr, acc[ni], 0, 0, 0);
            }
        }
        if (c < 7) {
#pragma unroll
            for (int i = 0; i < 2; i++)
                *(uint4*)&Vt[cur ^ 1][se[i]][sp[i]] = pre[i];
        }
        __syncthreads();
    }
    dsum += __shfl_xor(dsum, 16);
    dsum += __shfl_xor(dsum, 32);     // lanes with lane&15==r now hold row r's full sum
#pragma unroll
    for (int rr = 0; rr < 4; rr++) {
        float inv = 1.f / __shfl(dsum, q * 4 + rr, 64);   // D-row = q*4+rr
        size_t off = ((size_t)(b * D_ + row0 + q * 4 + rr)) * HID_ + h * OUT_ + eh * 32;
#pragma unroll
        for (int ni = 0; ni < 2; ni++)
            hnew[off + ni * 16 + r16] = acc[ni][rr] * inv;
    }
}

// ---------------------------------------------------------------------------
// 4) addln_k: h = LayerNorm(h + hnew)*g + b; fp32 + bf16 out.
//    One wave per row, shfl-only reductions. grid 2048 x 256.
// ---------------------------------------------------------------------------
__global__ __launch_bounds__(256) void addln_k(float* __restrict__ h,
                                               const float* __restrict__ hnew,
                                               const float* __restrict__ g,
                                               const float* __restrict__ bb,
                                               unsigned short* __restrict__ hbf) {
    int wave = threadIdx.x >> 6, lane = threadIdx.x & 63;
    size_t row = (size_t)blockIdx.x * 4 + wave;
    float4 a  = *(const float4*)&h[row * HID_ + lane * 4];
    float4 nv = *(const float4*)&hnew[row * HID_ + lane * 4];
    float4 v = {a.x + nv.x, a.y + nv.y, a.z + nv.z, a.w + nv.w};
    float s = v.x + v.y + v.z + v.w;
#pragma unroll
    for (int off = 1; off < 64; off <<= 1) s += __shfl_xor(s, off, 64);
    float mu = s * (1.f / HID_);
    float4 d = {v.x - mu, v.y - mu, v.z - mu, v.w - mu};
    float s2 = d.x * d.x + d.y * d.y + d.z * d.z + d.w * d.w;
#pragma unroll
    for (int off = 1; off < 64; off <<= 1) s2 += __shfl_xor(s2, off, 64);
    float rs = rsqrtf(s2 * (1.f / HID_) + EPS_);
    float4 gg = *(const float4*)&g[lane * 4];
    float4 bbv = *(const float4*)&bb[lane * 4];
    float4 res;
    res.x = d.x * rs * gg.x + bbv.x;
    res.y = d.y * rs * gg.y + bbv.y;
    res.z = d.z * rs * gg.z + bbv.z;
    res.w = d.w * rs * gg.w + bbv.w;
    *(float4*)&h[row * HID_ + lane * 4] = res;
    ushort4 pk = {f2bf(res.x), f2bf(res.y), f2bf(res.z), f2bf(res.w)};
    *(ushort4*)&hbf[row * HID_ + lane * 4] = pk;
}

// ---------------------------------------------------------------------------
extern "C" void kernel_launch(void* const* d_in, const int* in_sizes, int n_in,
                              void* d_out, int out_size, void* d_ws, size_t ws_size,
                              hipStream_t stream) {
    const float* X_obs = (const float*)d_in[0];
    const float* mask  = (const float*)d_in[1];
    const float* W_in  = (const float*)d_in[2];
    const float* b_in  = (const float*)d_in[3];
    const float* gat_W = (const float*)d_in[4];
    const float* gat_a = (const float*)d_in[5];
    const float* ln_g  = (const float*)d_in[6];
    const float* ln_b  = (const float*)d_in[7];
    const float* W_out = (const float*)d_in[8];
    const float* b_out = (const float*)d_in[9];
    float* out = (float*)d_out;

    // Workspace layout (r0 skeleton):
    //  [0,16M):   Ain bf16 (M x 1024); dead after gemm1, then:
    //             hwT bf16 [32][64][1024] at [0,4M), hnew fp32 [M][256] at [4,12M)
    //  [21M,29M): hbuf fp32 (M x 256)
    //  [29M,33M): hbf bf16 (M x 256)
    //  [33M,+):   Wt_in, Wcat, WtO (bf16), slb/srb (fp32), rmaxkey (uint[64])
    char* base = (char*)d_ws;
    unsigned short* Ain  = (unsigned short*)base;
    unsigned short* hwT  = (unsigned short*)base;
    float* hnew = (float*)(base + (4u << 20));
    float* hbuf = (float*)(base + (21u << 20));
    unsigned short* hbf   = (unsigned short*)(base + (29u << 20));
    unsigned short* Wt_in = (unsigned short*)(base + (33u << 20));
    unsigned short* Wcat  = Wt_in + (size_t)HID_ * KIN_;        // 256*1024
    unsigned short* WtO   = Wcat + (size_t)NL_ * HID_ * HID_;   // 2*256*256
    float* slb = (float*)(WtO + (size_t)T_ * HID_);             // 32*1024
    float* srb = slb + B_ * NH_ * D_;
    unsigned int* rmaxkey = (unsigned int*)(srb + B_ * NH_ * D_);  // [2][32]

    prep_k<<<2560, 256, 0, stream>>>(X_obs, mask, W_in, gat_W, W_out,
                                     Ain, Wt_in, Wcat, WtO, rmaxkey);

    // h = [X_mean|mask] @ W_in + b_in   (8192x1024)@(1024x256), fp32+bf16 out
    gemm_bf16_k<1><<<dim3(HID_ / 64, M_ / 64), 256, 0, stream>>>(
        Ain, Wt_in, b_in, hbuf, hbf, nullptr, nullptr, nullptr, nullptr,
        HID_, KIN_);

    for (int l = 0; l < NL_; l++) {
        // hW = h @ Wcat[l] -> hwT bf16 + fused s_l/s_r/rmax
        gemm_bf16_k<2><<<dim3(HID_ / 64, M_ / 64), 256, 0, stream>>>(
            hbf, Wcat + (size_t)l * HID_ * HID_, nullptr, nullptr, hwT,
            gat_a + (size_t)l * NH_ * 2 * OUT_, slb, srb, rmaxkey + l * 32,
            HID_, HID_);
        // split-e attention: full-m per block, normalized in-kernel -> hnew
        attn_k<<<dim3(B_ * NH_, D_ / 64, 2), 256, 0, stream>>>(
            hwT, slb, srb, rmaxkey + l * 32, hnew);
        // lean fused residual + LayerNorm
        addln_k<<<M_ / 4, 256, 0, stream>>>(hbuf, hnew,
                                            ln_g + (size_t)l * HID_,
                                            ln_b + (size_t)l * HID_, hbf);
    }

    // out = h @ W_out + b_out  (8192x256)@(256x512), fp32 out
    gemm_bf16_k<0><<<dim3(T_ / 64, M_ / 64), 256, 0, stream>>>(
        hbf, WtO, b_out, out, nullptr, nullptr, nullptr, nullptr, nullptr,
        T_, HID_);
}